// Round 1
// baseline (272.557 us; speedup 1.0000x reference)
//
#include <hip/hip_runtime.h>
#include <hip/hip_bf16.h>

// Problem constants
#define B_  2
#define S_  2048
#define E_  1024
#define H_  16
#define HD_ 64
#define T_  (B_*S_)   // 4096 token rows
#define F_  (3*E_)    // 3072 qkv features

using bf16 = __hip_bfloat16;
typedef __attribute__((ext_vector_type(8))) short bf16x8;
typedef __attribute__((ext_vector_type(4))) float f32x4;

__device__ inline short f2bf(float x) {
  __hip_bfloat16 h = __float2bfloat16(x);
  return __builtin_bit_cast(short, h);
}

__device__ inline void gload_lds16(const void* g, void* l) {
  __builtin_amdgcn_global_load_lds(
      (const __attribute__((address_space(1))) void*)g,
      (__attribute__((address_space(3))) void*)l, 16, 0, 0);
}

// ---------------- f32 -> bf16 convert (vectorized, 8 elems/thread) ----------
__global__ __launch_bounds__(256) void cvt_f32_bf16(
    const float* __restrict__ in, short* __restrict__ out, int n8) {
  int i = blockIdx.x * 256 + threadIdx.x;
  if (i >= n8) return;
  const float4* p = (const float4*)in + (size_t)i * 2;
  float4 a = p[0], b = p[1];
  bf16x8 r;
  r[0] = f2bf(a.x); r[1] = f2bf(a.y); r[2] = f2bf(a.z); r[3] = f2bf(a.w);
  r[4] = f2bf(b.x); r[5] = f2bf(b.y); r[6] = f2bf(b.z); r[7] = f2bf(b.w);
  *(bf16x8*)(out + (size_t)i * 8) = r;
}

// ---------------- NT GEMM: C[M,N] = A[M,K] * Bm[N,K]^T + bias ----------------
// 128x128 tile, BK=64, 4 waves (2x2), 16x16x32 bf16 MFMA, global_load_lds
// staging with XOR-swizzled source + swizzled ds_read (T2, rule #21).
__device__ inline void store_out(short* p, float v) { *p = f2bf(v); }
__device__ inline void store_out(float* p, float v) { *p = v; }

template<typename OutT>
__global__ __launch_bounds__(256) void gemm_nt(
    const short* __restrict__ A,   // M x K bf16
    const short* __restrict__ Bm,  // N x K bf16 (i.e. B^T layout)
    const float* __restrict__ bias,// N
    OutT* __restrict__ C,          // M x N
    int M, int N, int K) {
  __shared__ __align__(16) char sAB[32768];
  char* sA = sAB;
  char* sB = sAB + 16384;
  const int tid  = threadIdx.x;
  const int w    = tid >> 6, lane = tid & 63;
  const int lr   = lane & 15, g = lane >> 4;
  const int brow = blockIdx.y * 128, bcol = blockIdx.x * 128;
  const int wr   = (w >> 1) * 64,  wc   = (w & 1) * 64;

  f32x4 acc[4][4];
  #pragma unroll
  for (int i = 0; i < 4; ++i)
    #pragma unroll
    for (int j = 0; j < 4; ++j) acc[i][j] = (f32x4)0.0f;

  const size_t Kb = (size_t)K * 2;  // global row bytes
  const char* Ag = (const char*)A + (size_t)brow * Kb;
  const char* Bg = (const char*)Bm + (size_t)bcol * Kb;

  for (int k0 = 0; k0 < K; k0 += 64) {
    // stage A,B tiles: [128 rows][128 bytes], 4 issues each
    #pragma unroll
    for (int i = 0; i < 4; ++i) {
      int base = i * 4096 + w * 1024;       // wave-uniform LDS base
      int lb   = base + lane * 16;          // this lane's dest byte
      int r    = lb >> 7;
      int cb   = (lb & 127) ^ ((r & 7) << 4);  // inverse-swizzled source col
      gload_lds16(Ag + (size_t)r * Kb + (size_t)k0 * 2 + cb, sA + base);
      gload_lds16(Bg + (size_t)r * Kb + (size_t)k0 * 2 + cb, sB + base);
    }
    __syncthreads();
    #pragma unroll
    for (int ks = 0; ks < 2; ++ks) {
      bf16x8 af[4], bfr[4];
      #pragma unroll
      for (int m = 0; m < 4; ++m) {
        int row = wr + m * 16 + lr;
        int cb  = (ks * 64 + g * 16) ^ ((row & 7) << 4);
        af[m] = *(const bf16x8*)(sA + row * 128 + cb);
      }
      #pragma unroll
      for (int n = 0; n < 4; ++n) {
        int row = wc + n * 16 + lr;
        int cb  = (ks * 64 + g * 16) ^ ((row & 7) << 4);
        bfr[n] = *(const bf16x8*)(sB + row * 128 + cb);
      }
      #pragma unroll
      for (int m = 0; m < 4; ++m)
        #pragma unroll
        for (int n = 0; n < 4; ++n)
          acc[m][n] = __builtin_amdgcn_mfma_f32_16x16x32_bf16(
              af[m], bfr[n], acc[m][n], 0, 0, 0);
    }
    __syncthreads();
  }
  // epilogue: C row = (lane>>4)*4+j, col = lane&15 (m89-verified layout)
  #pragma unroll
  for (int n = 0; n < 4; ++n) {
    int f = bcol + wc + n * 16 + lr;
    float bv = bias[f];
    #pragma unroll
    for (int m = 0; m < 4; ++m) {
      int t0 = brow + wr + m * 16 + g * 4;
      #pragma unroll
      for (int j = 0; j < 4; ++j) {
        store_out(&C[(size_t)(t0 + j) * N + f], acc[m][n][j] + bv);
      }
    }
  }
}

// ---------------- Flash attention -------------------------------------------
// grid (32 qblks, H, B); 256 threads = 4 waves, each wave owns 16 query rows.
// K tile [64][64] bf16 (swizzled) via global_load_lds; V staged transposed via
// regs into Vt[feat][key] (swizzled); P routed through swizzled LDS.
__global__ __launch_bounds__(256) void attn_kernel(
    const short* __restrict__ qkv, short* __restrict__ ctx) {
  __shared__ __align__(16) char smem[24576];
  char* sK  = smem;          // 8KB: K[key][feat]
  char* sVt = smem + 8192;   // 8KB: V^T[feat][key]
  char* sP  = smem + 16384;  // 8KB: 4 waves x P[16][64]
  const int tid = threadIdx.x;
  const int w = tid >> 6, lane = tid & 63;
  const int lr = lane & 15, g = lane >> 4;
  const int qblk = blockIdx.x, h = blockIdx.y, b = blockIdx.z;

  const size_t rowB = (size_t)F_ * 2;  // 6144 bytes per token row
  const char* base = (const char*)qkv + (size_t)b * S_ * rowB + (size_t)h * 384;

  // Q fragments (held in regs for whole kernel); A-layout row=lane&15
  const int qrow = qblk * 64 + w * 16 + lr;
  const char* qp = base + (size_t)qrow * rowB;
  bf16x8 qf0 = *(const bf16x8*)(qp + g * 16);
  bf16x8 qf1 = *(const bf16x8*)(qp + 64 + g * 16);

  float m_run[4], l_run[4];
  f32x4 o[4];
  #pragma unroll
  for (int j = 0; j < 4; ++j) { m_run[j] = -1e30f; l_run[j] = 0.0f; }
  #pragma unroll
  for (int n = 0; n < 4; ++n) o[n] = (f32x4)0.0f;

  const int vkey = tid & 63, vfb = (tid >> 6) * 16;
  char* sPw = sP + w * 2048;

  for (int kt = 0; kt < 32; ++kt) {
    const char* kvbase = base + (size_t)(kt * 64) * rowB;
    // stage K tile (offset +64 elems = +128B within row)
    #pragma unroll
    for (int i = 0; i < 2; ++i) {
      int lbase = i * 4096 + w * 1024;
      int lb = lbase + lane * 16;
      int r  = lb >> 7;
      int cb = (lb & 127) ^ ((r & 7) << 4);
      gload_lds16(kvbase + (size_t)r * rowB + 128 + cb, sK + lbase);
    }
    // stage V transposed (offset +128 elems = +256B within row)
    {
      const char* vp = kvbase + (size_t)vkey * rowB + 256 + vfb * 2;
      bf16x8 v0 = *(const bf16x8*)(vp);
      bf16x8 v1 = *(const bf16x8*)(vp + 16);
      #pragma unroll
      for (int j = 0; j < 8; ++j) {
        int f0 = vfb + j;
        *(short*)(sVt + f0 * 128 + ((vkey * 2) ^ ((f0 & 7) << 4))) = v0[j];
        int f1 = vfb + 8 + j;
        *(short*)(sVt + f1 * 128 + ((vkey * 2) ^ ((f1 & 7) << 4))) = v1[j];
      }
    }
    __syncthreads();

    // QK^T: scores[16 q-rows][64 keys] as 4 col-fragments
    f32x4 s[4];
    #pragma unroll
    for (int n = 0; n < 4; ++n) s[n] = (f32x4)0.0f;
    #pragma unroll
    for (int ks = 0; ks < 2; ++ks) {
      bf16x8 qf = ks ? qf1 : qf0;
      #pragma unroll
      for (int n = 0; n < 4; ++n) {
        int row = n * 16 + lr;
        int cb  = (ks * 64 + g * 16) ^ ((row & 7) << 4);
        bf16x8 kf = *(const bf16x8*)(sK + row * 128 + cb);
        s[n] = __builtin_amdgcn_mfma_f32_16x16x32_bf16(qf, kf, s[n], 0, 0, 0);
      }
    }

    // online softmax; row r = g*4+j held by the 16 lanes of group g
    #pragma unroll
    for (int j = 0; j < 4; ++j) {
      float s0 = s[0][j] * 0.125f, s1 = s[1][j] * 0.125f;
      float s2 = s[2][j] * 0.125f, s3 = s[3][j] * 0.125f;
      float mx = fmaxf(fmaxf(s0, s1), fmaxf(s2, s3));
      mx = fmaxf(mx, __shfl_xor(mx, 1));
      mx = fmaxf(mx, __shfl_xor(mx, 2));
      mx = fmaxf(mx, __shfl_xor(mx, 4));
      mx = fmaxf(mx, __shfl_xor(mx, 8));
      float mn = fmaxf(m_run[j], mx);
      float al = __expf(m_run[j] - mn);
      m_run[j] = mn;
      float p0 = __expf(s0 - mn), p1 = __expf(s1 - mn);
      float p2 = __expf(s2 - mn), p3 = __expf(s3 - mn);
      float rs = p0 + p1 + p2 + p3;
      rs += __shfl_xor(rs, 1);
      rs += __shfl_xor(rs, 2);
      rs += __shfl_xor(rs, 4);
      rs += __shfl_xor(rs, 8);
      l_run[j] = l_run[j] * al + rs;
      #pragma unroll
      for (int n = 0; n < 4; ++n) o[n][j] *= al;
      int row = g * 4 + j;
      int sw  = (row & 7) << 4;
      *(short*)(sPw + row * 128 + (((0 * 16 + lr) * 2) ^ sw)) = f2bf(p0);
      *(short*)(sPw + row * 128 + (((1 * 16 + lr) * 2) ^ sw)) = f2bf(p1);
      *(short*)(sPw + row * 128 + (((2 * 16 + lr) * 2) ^ sw)) = f2bf(p2);
      *(short*)(sPw + row * 128 + (((3 * 16 + lr) * 2) ^ sw)) = f2bf(p3);
    }

    // PV: o += P[16][64keys] * V[64keys][64feat]
    #pragma unroll
    for (int ks = 0; ks < 2; ++ks) {
      int cbp = (ks * 64 + g * 16) ^ ((lr & 7) << 4);
      bf16x8 pf = *(const bf16x8*)(sPw + lr * 128 + cbp);
      #pragma unroll
      for (int n = 0; n < 4; ++n) {
        int row = n * 16 + lr;  // feature row in Vt
        int cb  = (ks * 64 + g * 16) ^ ((row & 7) << 4);
        bf16x8 vf = *(const bf16x8*)(sVt + row * 128 + cb);
        o[n] = __builtin_amdgcn_mfma_f32_16x16x32_bf16(pf, vf, o[n], 0, 0, 0);
      }
    }
    __syncthreads();
  }

  // normalize + write ctx[t][h*64+f] bf16
  #pragma unroll
  for (int j = 0; j < 4; ++j) {
    float inv = 1.0f / l_run[j];
    int t = b * S_ + qblk * 64 + w * 16 + g * 4 + j;
    short* crow = ctx + (size_t)t * E_ + h * 64;
    #pragma unroll
    for (int n = 0; n < 4; ++n) {
      crow[n * 16 + lr] = f2bf(o[n][j] * inv);
    }
  }
}

// ---------------- launch -----------------------------------------------------
extern "C" void kernel_launch(void* const* d_in, const int* in_sizes, int n_in,
                              void* d_out, int out_size, void* d_ws, size_t ws_size,
                              hipStream_t stream) {
  const float* x    = (const float*)d_in[0];
  const float* Wqkv = (const float*)d_in[1];
  const float* bqkv = (const float*)d_in[2];
  const float* Wout = (const float*)d_in[3];
  const float* bout = (const float*)d_in[4];

  char* ws = (char*)d_ws;
  short* xb    = (short*)(ws);                          // 8 MB
  short* wqkvb = (short*)(ws + 8388608);                // 6 MB
  short* woutb = (short*)(ws + 8388608 + 6291456);      // 2 MB
  short* qkvb  = (short*)(ws + 16777216);               // 24 MB
  short* ctx   = (short*)(ws + 16777216 + 25165824);    // 8 MB  (total 48 MB)

  // f32 -> bf16 converts
  cvt_f32_bf16<<<2048, 256, 0, stream>>>(x, xb, (T_ * E_) / 8);
  cvt_f32_bf16<<<1536, 256, 0, stream>>>(Wqkv, wqkvb, (F_ * E_) / 8);
  cvt_f32_bf16<<<512, 256, 0, stream>>>(Wout, woutb, (E_ * E_) / 8);

  // QKV projection: [4096,3072] = xb[4096,1024] * Wqkv[3072,1024]^T + b
  gemm_nt<short><<<dim3(F_ / 128, T_ / 128), 256, 0, stream>>>(
      xb, wqkvb, bqkv, qkvb, T_, F_, E_);

  // attention
  attn_kernel<<<dim3(S_ / 64, H_, B_), 256, 0, stream>>>(qkvb, ctx);

  // output projection: [4096,1024] = ctx[4096,1024] * Wout[1024,1024]^T + b
  gemm_nt<float><<<dim3(E_ / 128, T_ / 128), 256, 0, stream>>>(
      ctx, woutb, bout, (float*)d_out, T_, E_, E_);
}

// Round 4
// 255.845 us; speedup vs baseline: 1.0653x; 1.0653x over previous
//
#include <hip/hip_runtime.h>
#include <hip/hip_bf16.h>

// Problem constants
#define B_  2
#define S_  2048
#define E_  1024
#define H_  16
#define HD_ 64
#define T_  (B_*S_)   // 4096 token rows
#define F_  (3*E_)    // 3072 qkv features

using bf16 = __hip_bfloat16;
typedef __attribute__((ext_vector_type(8))) short bf16x8;
typedef __attribute__((ext_vector_type(4))) short short4v;
typedef __attribute__((ext_vector_type(4))) float f32x4;
typedef __attribute__((ext_vector_type(16))) float f32x16;
typedef __attribute__((ext_vector_type(4))) int i32x4;
typedef __attribute__((ext_vector_type(2))) unsigned int u32x2;

__device__ inline short f2bf(float x) {
  __hip_bfloat16 h = __float2bfloat16(x);
  return __builtin_bit_cast(short, h);
}
__device__ inline float bf2f(short x) {
  return __bfloat162float(__builtin_bit_cast(__hip_bfloat16, x));
}
// Pack two floats to bf16 pair (RNE via __float2bfloat16; unambiguous).
__device__ inline int pack2(float lo, float hig) {
  return (int)((unsigned short)f2bf(lo) |
               ((unsigned int)(unsigned short)f2bf(hig) << 16));
}

__device__ inline void gload_lds16(const void* g, void* l) {
  __builtin_amdgcn_global_load_lds(
      (const __attribute__((address_space(1))) void*)g,
      (__attribute__((address_space(3))) void*)l, 16, 0, 0);
}

// ---------------- f32 -> bf16 convert (vectorized, 8 elems/thread) ----------
__global__ __launch_bounds__(256) void cvt_f32_bf16(
    const float* __restrict__ in, short* __restrict__ out, int n8) {
  int i = blockIdx.x * 256 + threadIdx.x;
  if (i >= n8) return;
  const float4* p = (const float4*)in + (size_t)i * 2;
  float4 a = p[0], b = p[1];
  bf16x8 r;
  r[0] = f2bf(a.x); r[1] = f2bf(a.y); r[2] = f2bf(a.z); r[3] = f2bf(a.w);
  r[4] = f2bf(b.x); r[5] = f2bf(b.y); r[6] = f2bf(b.z); r[7] = f2bf(b.w);
  *(bf16x8*)(out + (size_t)i * 8) = r;
}

// ---------------- NT GEMM: C[M,N] = A[M,K] * Bm[N,K]^T + bias ----------------
__device__ inline void store_out(short* p, float v) { *p = f2bf(v); }
__device__ inline void store_out(float* p, float v) { *p = v; }

template<typename OutT>
__global__ __launch_bounds__(256) void gemm_nt(
    const short* __restrict__ A,   // M x K bf16
    const short* __restrict__ Bm,  // N x K bf16 (i.e. B^T layout)
    const float* __restrict__ bias,// N
    OutT* __restrict__ C,          // M x N
    int M, int N, int K) {
  __shared__ __align__(16) char sAB[32768];
  char* sA = sAB;
  char* sB = sAB + 16384;
  const int tid  = threadIdx.x;
  const int w    = tid >> 6, lane = tid & 63;
  const int lr   = lane & 15, g = lane >> 4;
  const int brow = blockIdx.y * 128, bcol = blockIdx.x * 128;
  const int wr   = (w >> 1) * 64,  wc   = (w & 1) * 64;

  f32x4 acc[4][4];
  #pragma unroll
  for (int i = 0; i < 4; ++i)
    #pragma unroll
    for (int j = 0; j < 4; ++j) acc[i][j] = (f32x4)0.0f;

  const size_t Kb = (size_t)K * 2;  // global row bytes
  const char* Ag = (const char*)A + (size_t)brow * Kb;
  const char* Bg = (const char*)Bm + (size_t)bcol * Kb;

  for (int k0 = 0; k0 < K; k0 += 64) {
    #pragma unroll
    for (int i = 0; i < 4; ++i) {
      int base = i * 4096 + w * 1024;       // wave-uniform LDS base
      int lb   = base + lane * 16;          // this lane's dest byte
      int r    = lb >> 7;
      int cb   = (lb & 127) ^ ((r & 7) << 4);  // inverse-swizzled source col
      gload_lds16(Ag + (size_t)r * Kb + (size_t)k0 * 2 + cb, sA + base);
      gload_lds16(Bg + (size_t)r * Kb + (size_t)k0 * 2 + cb, sB + base);
    }
    __syncthreads();
    #pragma unroll
    for (int ks = 0; ks < 2; ++ks) {
      bf16x8 af[4], bfr[4];
      #pragma unroll
      for (int m = 0; m < 4; ++m) {
        int row = wr + m * 16 + lr;
        int cb  = (ks * 64 + g * 16) ^ ((row & 7) << 4);
        af[m] = *(const bf16x8*)(sA + row * 128 + cb);
      }
      #pragma unroll
      for (int n = 0; n < 4; ++n) {
        int row = wc + n * 16 + lr;
        int cb  = (ks * 64 + g * 16) ^ ((row & 7) << 4);
        bfr[n] = *(const bf16x8*)(sB + row * 128 + cb);
      }
      #pragma unroll
      for (int m = 0; m < 4; ++m)
        #pragma unroll
        for (int n = 0; n < 4; ++n)
          acc[m][n] = __builtin_amdgcn_mfma_f32_16x16x32_bf16(
              af[m], bfr[n], acc[m][n], 0, 0, 0);
    }
    __syncthreads();
  }
  #pragma unroll
  for (int n = 0; n < 4; ++n) {
    int f = bcol + wc + n * 16 + lr;
    float bv = bias[f];
    #pragma unroll
    for (int m = 0; m < 4; ++m) {
      int t0 = brow + wr + m * 16 + g * 4;
      #pragma unroll
      for (int j = 0; j < 4; ++j) {
        store_out(&C[(size_t)(t0 + j) * N + f], acc[m][n][j] + bv);
      }
    }
  }
}

// ---------------- Flash attention (32x32 swapped MFMA, shfl-based exchange) --
// grid (16 qblks, H, B); 256 threads = 4 waves, each wave owns 32 query rows.
// Swapped QK^T: st = mfma(K,Q) -> C[key][q], scores lane-local per q-column.
// All cross-lane exchange via __shfl_xor(.,32) (unambiguous semantics).
__global__ __launch_bounds__(256) void attn_kernel(
    const short* __restrict__ qkv, short* __restrict__ ctx) {
  __shared__ __align__(16) char smem[16384];
  char* sK  = smem;          // 8KB: K[64key][64d], XOR-swizzled
  char* sVt = smem + 8192;   // 8KB: V^T[64f][64key], XOR-swizzled
  const int tid = threadIdx.x;
  const int w = tid >> 6, lane = tid & 63;
  const int ql = lane & 31, hi = lane >> 5;
  const int qblk = blockIdx.x, h = blockIdx.y, b = blockIdx.z;

  const size_t rowB = (size_t)F_ * 2;  // 6144 bytes per token row
  const char* base = (const char*)qkv + (size_t)b * S_ * rowB + (size_t)h * 384;

  // Q row for this lane's q-column; pre-scale by 1/sqrt(64) * log2(e)
  const int qrow = qblk * 128 + w * 32 + ql;   // row within batch
  const char* qp = base + (size_t)qrow * rowB;
  bf16x8 qf[4];
  #pragma unroll
  for (int ks = 0; ks < 4; ++ks) {
    bf16x8 t = *(const bf16x8*)(qp + ks * 32 + hi * 16);
    #pragma unroll
    for (int j = 0; j < 8; ++j) t[j] = f2bf(bf2f(t[j]) * 0.180336880f);
    qf[ks] = t;
  }

  // V staging role: 4 keys x 4 feats per thread
  const int vkg = tid >> 4;      // key group (4 keys)
  const int vfg = tid & 15;      // feat group (4 feats)

  float m_run = -3.0e38f, l_run = 0.0f;
  f32x16 ot0 = (f32x16)0.0f, ot1 = (f32x16)0.0f;  // O^T[f][q], f-halves

  for (int kt = 0; kt < 32; ++kt) {
    const char* kvbase = base + (size_t)(kt * 64) * rowB;
    // ---- stage K [64key][64d] via global_load_lds (linear dest, inv-swz src)
    #pragma unroll
    for (int i = 0; i < 2; ++i) {
      int lbase = i * 4096 + w * 1024;
      int lb = lbase + lane * 16;
      int r  = lb >> 7;
      int cb = (lb & 127) ^ ((r & 7) << 4);
      gload_lds16(kvbase + (size_t)r * rowB + 128 + cb, sK + lbase);
    }
    // ---- stage V transposed: 4x4 reg transpose, ds_write_b64
    {
      const char* vp = kvbase + 256 + vfg * 8;
      short4v v0 = *(const short4v*)(vp + (size_t)(vkg * 4 + 0) * rowB);
      short4v v1 = *(const short4v*)(vp + (size_t)(vkg * 4 + 1) * rowB);
      short4v v2 = *(const short4v*)(vp + (size_t)(vkg * 4 + 2) * rowB);
      short4v v3 = *(const short4v*)(vp + (size_t)(vkg * 4 + 3) * rowB);
      #pragma unroll
      for (int f = 0; f < 4; ++f) {
        int fr = vfg * 4 + f;
        u32x2 dw;
        dw[0] = (unsigned short)v0[f] | ((unsigned int)(unsigned short)v1[f] << 16);
        dw[1] = (unsigned short)v2[f] | ((unsigned int)(unsigned short)v3[f] << 16);
        *(u32x2*)(sVt + fr * 128 + ((vkg * 8) ^ ((fr & 7) << 4))) = dw;
      }
    }
    __syncthreads();

    // ---- QK^T swapped: st = mfma(K, Q) -> C[key][q]
    f32x16 st0 = (f32x16)0.0f, st1 = (f32x16)0.0f;
    __builtin_amdgcn_s_setprio(1);
    #pragma unroll
    for (int ks = 0; ks < 4; ++ks) {
      int cb = (ks * 32 + hi * 16) ^ ((ql & 7) << 4);
      bf16x8 k0 = *(const bf16x8*)(sK + ql * 128 + cb);
      bf16x8 k1 = *(const bf16x8*)(sK + (ql + 32) * 128 + cb);
      st0 = __builtin_amdgcn_mfma_f32_32x32x16_bf16(k0, qf[ks], st0, 0, 0, 0);
      st1 = __builtin_amdgcn_mfma_f32_32x32x16_bf16(k1, qf[ks], st1, 0, 0, 0);
    }
    __builtin_amdgcn_s_setprio(0);

    // ---- in-register online softmax over 64 keys (32 here + 32 at partner)
    float mx = fmaxf(st0[0], st1[0]);
    #pragma unroll
    for (int r = 1; r < 16; ++r) mx = fmaxf(mx, fmaxf(st0[r], st1[r]));
    mx = fmaxf(mx, __shfl_xor(mx, 32));
    float mn = fmaxf(m_run, mx);
    float al = exp2f(m_run - mn);
    m_run = mn;
    float p0[16], p1[16];
    float rs = 0.0f;
    #pragma unroll
    for (int r = 0; r < 16; ++r) {
      p0[r] = exp2f(st0[r] - mn);
      p1[r] = exp2f(st1[r] - mn);
      rs += p0[r] + p1[r];
    }
    rs += __shfl_xor(rs, 32);
    l_run = l_run * al + rs;
    #pragma unroll
    for (int r = 0; r < 16; ++r) { ot0[r] *= al; ot1[r] *= al; }

    // ---- exchange partner's p-arrays (elementwise, static indices)
    float q0[16], q1[16];
    #pragma unroll
    for (int r = 0; r < 16; ++r) q0[r] = __shfl_xor(p0[r], 32);
    #pragma unroll
    for (int r = 0; r < 16; ++r) q1[r] = __shfl_xor(p1[r], 32);

    // ---- pack P A-fragments: paw[kk] elem j = P[key = kk*16 + hi*8 + j][ql].
    // Home of key k: half hb=(k>>2)&1, reg r=(k&3)|((k>>3)<<2). For our keys:
    // hb = j>>2, r = (j&3) + 8*(kk&1) + 4*hi. All indices static; partner
    // values come from q-arrays (same static index; selected by cndmask).
    i32x4 paw0, paw1, paw2, paw3;
#define BUILD_PAW(dst, pp, qq, bb) do {                                   \
      float v0_ = hi ? qq[(bb)+4] : pp[(bb)+0];                           \
      float v1_ = hi ? qq[(bb)+5] : pp[(bb)+1];                           \
      float v2_ = hi ? qq[(bb)+6] : pp[(bb)+2];                           \
      float v3_ = hi ? qq[(bb)+7] : pp[(bb)+3];                           \
      float v4_ = hi ? pp[(bb)+4] : qq[(bb)+0];                           \
      float v5_ = hi ? pp[(bb)+5] : qq[(bb)+1];                           \
      float v6_ = hi ? pp[(bb)+6] : qq[(bb)+2];                           \
      float v7_ = hi ? pp[(bb)+7] : qq[(bb)+3];                           \
      dst[0] = pack2(v0_, v1_); dst[1] = pack2(v2_, v3_);                 \
      dst[2] = pack2(v4_, v5_); dst[3] = pack2(v6_, v7_); } while (0)
    BUILD_PAW(paw0, p0, q0, 0);
    BUILD_PAW(paw1, p0, q0, 8);
    BUILD_PAW(paw2, p1, q1, 0);
    BUILD_PAW(paw3, p1, q1, 8);
#undef BUILD_PAW

    // ---- PV: ot = mfma(V, P) -> C[f][q], accumulate over 4 key-slots
    __builtin_amdgcn_s_setprio(1);
    #pragma unroll
    for (int ks = 0; ks < 4; ++ks) {
      int cb = (ks * 32 + hi * 16) ^ ((ql & 7) << 4);
      bf16x8 pf = __builtin_bit_cast(
          bf16x8, ks == 0 ? paw0 : ks == 1 ? paw1 : ks == 2 ? paw2 : paw3);
      bf16x8 v0 = *(const bf16x8*)(sVt + ql * 128 + cb);
      bf16x8 v1 = *(const bf16x8*)(sVt + (ql + 32) * 128 + cb);
      ot0 = __builtin_amdgcn_mfma_f32_32x32x16_bf16(v0, pf, ot0, 0, 0, 0);
      ot1 = __builtin_amdgcn_mfma_f32_32x32x16_bf16(v1, pf, ot1, 0, 0, 0);
    }
    __builtin_amdgcn_s_setprio(0);
    __syncthreads();
  }

  // ---- epilogue: normalize, pack bf16 pairs, store
  float inv = 1.0f / l_run;
  short* crow = ctx + ((size_t)b * S_ + qrow) * E_ + h * 64;
  #pragma unroll
  for (int i = 0; i < 8; ++i) {
    int f0 = ((2 * i) & 3) + 8 * (i >> 1) + 4 * hi;  // even, pair (f0, f0+1)
    int w0 = pack2(ot0[2 * i] * inv, ot0[2 * i + 1] * inv);
    int w1 = pack2(ot1[2 * i] * inv, ot1[2 * i + 1] * inv);
    *(int*)(crow + f0)      = w0;
    *(int*)(crow + f0 + 32) = w1;
  }
}

// ---------------- launch -----------------------------------------------------
extern "C" void kernel_launch(void* const* d_in, const int* in_sizes, int n_in,
                              void* d_out, int out_size, void* d_ws, size_t ws_size,
                              hipStream_t stream) {
  const float* x    = (const float*)d_in[0];
  const float* Wqkv = (const float*)d_in[1];
  const float* bqkv = (const float*)d_in[2];
  const float* Wout = (const float*)d_in[3];
  const float* bout = (const float*)d_in[4];

  char* ws = (char*)d_ws;
  short* xb    = (short*)(ws);                          // 8 MB
  short* wqkvb = (short*)(ws + 8388608);                // 6 MB
  short* woutb = (short*)(ws + 8388608 + 6291456);      // 2 MB
  short* qkvb  = (short*)(ws + 16777216);               // 24 MB
  short* ctx   = (short*)(ws + 16777216 + 25165824);    // 8 MB  (total 48 MB)

  cvt_f32_bf16<<<2048, 256, 0, stream>>>(x, xb, (T_ * E_) / 8);
  cvt_f32_bf16<<<1536, 256, 0, stream>>>(Wqkv, wqkvb, (F_ * E_) / 8);
  cvt_f32_bf16<<<512, 256, 0, stream>>>(Wout, woutb, (E_ * E_) / 8);

  gemm_nt<short><<<dim3(F_ / 128, T_ / 128), 256, 0, stream>>>(
      xb, wqkvb, bqkv, qkvb, T_, F_, E_);

  attn_kernel<<<dim3(S_ / 128, H_, B_), 256, 0, stream>>>(qkvb, ctx);

  gemm_nt<float><<<dim3(E_ / 128, T_ / 128), 256, 0, stream>>>(
      ctx, woutb, bout, (float*)d_out, T_, E_, E_);
}

// Round 6
// 233.996 us; speedup vs baseline: 1.1648x; 1.0934x over previous
//
#include <hip/hip_runtime.h>
#include <hip/hip_bf16.h>

// Problem constants
#define B_  2
#define S_  2048
#define E_  1024
#define H_  16
#define HD_ 64
#define T_  (B_*S_)   // 4096 token rows
#define F_  (3*E_)    // 3072 qkv features

// Row-keyed LDS XOR swizzle, 16B granularity + row-bit3 into col-bit5 so that
// 8B V-transpose writes cover all 32 banks (round-4 fix).
#define SW(r) ((((r) & 7) << 4) ^ (((r) & 8) << 2))

using bf16 = __hip_bfloat16;
typedef __attribute__((ext_vector_type(8))) short bf16x8;
typedef __attribute__((ext_vector_type(4))) short short4v;
typedef __attribute__((ext_vector_type(4))) float f32x4;
typedef __attribute__((ext_vector_type(16))) float f32x16;
typedef __attribute__((ext_vector_type(4))) int i32x4;
typedef __attribute__((ext_vector_type(2))) unsigned int u32x2;

__device__ inline short f2bf(float x) {
  __hip_bfloat16 h = __float2bfloat16(x);
  return __builtin_bit_cast(short, h);
}
__device__ inline float bf2f(short x) {
  return __bfloat162float(__builtin_bit_cast(__hip_bfloat16, x));
}
// Pack two floats into a bf16 pair word (low = first), RNE per element.
__device__ inline int pk2(float lo, float hig) {
  return (int)((unsigned short)f2bf(lo) |
               ((unsigned int)(unsigned short)f2bf(hig) << 16));
}

__device__ inline void gload_lds16(const void* g, void* l) {
  __builtin_amdgcn_global_load_lds(
      (const __attribute__((address_space(1))) void*)g,
      (__attribute__((address_space(3))) void*)l, 16, 0, 0);
}

// ---------------- f32 -> bf16 convert (vectorized, 8 elems/thread) ----------
__global__ __launch_bounds__(256) void cvt_f32_bf16(
    const float* __restrict__ in, short* __restrict__ out, int n8) {
  int i = blockIdx.x * 256 + threadIdx.x;
  if (i >= n8) return;
  const float4* p = (const float4*)in + (size_t)i * 2;
  float4 a = p[0], b = p[1];
  bf16x8 r;
  r[0] = f2bf(a.x); r[1] = f2bf(a.y); r[2] = f2bf(a.z); r[3] = f2bf(a.w);
  r[4] = f2bf(b.x); r[5] = f2bf(b.y); r[6] = f2bf(b.z); r[7] = f2bf(b.w);
  *(bf16x8*)(out + (size_t)i * 8) = r;
}

// ---------------- NT GEMM: C[M,N] = A[M,K] * Bm[N,K]^T + bias ----------------
__device__ inline void store_out(short* p, float v) { *p = f2bf(v); }
__device__ inline void store_out(float* p, float v) { *p = v; }

template<typename OutT>
__global__ __launch_bounds__(256) void gemm_nt(
    const short* __restrict__ A,   // M x K bf16
    const short* __restrict__ Bm,  // N x K bf16 (i.e. B^T layout)
    const float* __restrict__ bias,// N
    OutT* __restrict__ C,          // M x N
    int M, int N, int K) {
  __shared__ __align__(16) char sAB[32768];
  char* sA = sAB;
  char* sB = sAB + 16384;
  const int tid  = threadIdx.x;
  const int w    = tid >> 6, lane = tid & 63;
  const int lr   = lane & 15, g = lane >> 4;
  const int brow = blockIdx.y * 128, bcol = blockIdx.x * 128;
  const int wr   = (w >> 1) * 64,  wc   = (w & 1) * 64;

  f32x4 acc[4][4];
  #pragma unroll
  for (int i = 0; i < 4; ++i)
    #pragma unroll
    for (int j = 0; j < 4; ++j) acc[i][j] = (f32x4)0.0f;

  const size_t Kb = (size_t)K * 2;  // global row bytes
  const char* Ag = (const char*)A + (size_t)brow * Kb;
  const char* Bg = (const char*)Bm + (size_t)bcol * Kb;

  for (int k0 = 0; k0 < K; k0 += 64) {
    #pragma unroll
    for (int i = 0; i < 4; ++i) {
      int base = i * 4096 + w * 1024;       // wave-uniform LDS base
      int lb   = base + lane * 16;          // this lane's dest byte
      int r    = lb >> 7;
      int cb   = (lb & 127) ^ ((r & 7) << 4);  // inverse-swizzled source col
      gload_lds16(Ag + (size_t)r * Kb + (size_t)k0 * 2 + cb, sA + base);
      gload_lds16(Bg + (size_t)r * Kb + (size_t)k0 * 2 + cb, sB + base);
    }
    __syncthreads();
    #pragma unroll
    for (int ks = 0; ks < 2; ++ks) {
      bf16x8 af[4], bfr[4];
      #pragma unroll
      for (int m = 0; m < 4; ++m) {
        int row = wr + m * 16 + lr;
        int cb  = (ks * 64 + g * 16) ^ ((row & 7) << 4);
        af[m] = *(const bf16x8*)(sA + row * 128 + cb);
      }
      #pragma unroll
      for (int n = 0; n < 4; ++n) {
        int row = wc + n * 16 + lr;
        int cb  = (ks * 64 + g * 16) ^ ((row & 7) << 4);
        bfr[n] = *(const bf16x8*)(sB + row * 128 + cb);
      }
      #pragma unroll
      for (int m = 0; m < 4; ++m)
        #pragma unroll
        for (int n = 0; n < 4; ++n)
          acc[m][n] = __builtin_amdgcn_mfma_f32_16x16x32_bf16(
              af[m], bfr[n], acc[m][n], 0, 0, 0);
    }
    __syncthreads();
  }
  #pragma unroll
  for (int n = 0; n < 4; ++n) {
    int f = bcol + wc + n * 16 + lr;
    float bv = bias[f];
    #pragma unroll
    for (int m = 0; m < 4; ++m) {
      int t0 = brow + wr + m * 16 + g * 4;
      #pragma unroll
      for (int j = 0; j < 4; ++j) {
        store_out(&C[(size_t)(t0 + j) * N + f], acc[m][n][j] + bv);
      }
    }
  }
}

// ---------------- Flash attention -------------------------------------------
// 32x32 swapped MFMA, double-buffered K/V LDS, 2-phase pipeline, defer-max.
// grid (16 qblks, H, B); 256 threads = 4 waves, each wave owns 32 query rows.
__global__ __launch_bounds__(256) void attn_kernel(
    const short* __restrict__ qkv, short* __restrict__ ctx) {
  __shared__ __align__(16) char smem[32768];  // 2 bufs x (8K sK + 8K sVt)
  const int tid = threadIdx.x;
  const int w = tid >> 6, lane = tid & 63;
  const int ql = lane & 31, hi = lane >> 5;
  const int qblk = blockIdx.x, h = blockIdx.y, b = blockIdx.z;

  const size_t rowB = (size_t)F_ * 2;  // 6144 bytes per token row
  const char* base = (const char*)qkv + (size_t)b * S_ * rowB + (size_t)h * 384;

  // Q row for this lane's q-column; pre-scale by 1/sqrt(64) * log2(e)
  const int qrow = qblk * 128 + w * 32 + ql;   // row within batch
  const char* qp = base + (size_t)qrow * rowB;
  bf16x8 qf[4];
  #pragma unroll
  for (int ks = 0; ks < 4; ++ks) {
    bf16x8 t = *(const bf16x8*)(qp + ks * 32 + hi * 16);
    #pragma unroll
    for (int j = 0; j < 8; ++j) t[j] = f2bf(bf2f(t[j]) * 0.180336880f);
    qf[ks] = t;
  }

  // V staging roles: thread loads 4 keys x 4 feats (coalesced on feat dim)
  const int vkg = tid >> 4;      // key group (keys vkg*4..+3)
  const int vfg = tid & 15;      // feat group (feats vfg*4..+3)

  float m_run = -3.0e38f, l_run = 0.0f;
  f32x16 ot0 = (f32x16)0.0f, ot1 = (f32x16)0.0f;  // O^T[f][q], f-halves

  // ---- prologue: stage tile 0 into buf 0
  {
    #pragma unroll
    for (int i = 0; i < 2; ++i) {
      int lbase = i * 4096 + w * 1024;
      int lb = lbase + lane * 16;
      int r  = lb >> 7;
      int cb = (lb & 127) ^ SW(r);
      gload_lds16(base + (size_t)r * rowB + 128 + cb, smem + lbase);
    }
    const char* vp = base + 256 + vfg * 8;
    short4v v0 = *(const short4v*)(vp + (size_t)(vkg * 4 + 0) * rowB);
    short4v v1 = *(const short4v*)(vp + (size_t)(vkg * 4 + 1) * rowB);
    short4v v2 = *(const short4v*)(vp + (size_t)(vkg * 4 + 2) * rowB);
    short4v v3 = *(const short4v*)(vp + (size_t)(vkg * 4 + 3) * rowB);
    char* dvt = smem + 8192;
    #pragma unroll
    for (int f = 0; f < 4; ++f) {
      int fr = vfg * 4 + f;
      u32x2 dw;
      dw[0] = (unsigned short)v0[f] | ((unsigned int)(unsigned short)v1[f] << 16);
      dw[1] = (unsigned short)v2[f] | ((unsigned int)(unsigned short)v3[f] << 16);
      *(u32x2*)(dvt + fr * 128 + ((vkg * 8) ^ SW(fr))) = dw;
    }
  }
  __syncthreads();

  int cur = 0;
  for (int kt = 0; kt < 32; ++kt) {
    const int nxt = cur ^ 1;
    const char* sK  = smem + cur * 16384;
    const char* sVt = sK + 8192;

    // ---- issue next tile's loads early (hide under compute)
    short4v nv0, nv1, nv2, nv3;
    const char* nkvb = base + (size_t)((kt + 1) * 64) * rowB;
    if (kt < 31) {
      #pragma unroll
      for (int i = 0; i < 2; ++i) {
        int lbase = i * 4096 + w * 1024;
        int lb = lbase + lane * 16;
        int r  = lb >> 7;
        int cb = (lb & 127) ^ SW(r);
        gload_lds16(nkvb + (size_t)r * rowB + 128 + cb,
                    smem + nxt * 16384 + lbase);
      }
      const char* vp = nkvb + 256 + vfg * 8;
      nv0 = *(const short4v*)(vp + (size_t)(vkg * 4 + 0) * rowB);
      nv1 = *(const short4v*)(vp + (size_t)(vkg * 4 + 1) * rowB);
      nv2 = *(const short4v*)(vp + (size_t)(vkg * 4 + 2) * rowB);
      nv3 = *(const short4v*)(vp + (size_t)(vkg * 4 + 3) * rowB);
    }

    // ---- QK^T swapped: st = mfma(K, Q) -> C[key][q]
    f32x16 st0 = (f32x16)0.0f, st1 = (f32x16)0.0f;
    __builtin_amdgcn_s_setprio(1);
    #pragma unroll
    for (int ks = 0; ks < 4; ++ks) {
      int cb = (ks * 32 + hi * 16) ^ SW(ql);
      bf16x8 k0 = *(const bf16x8*)(sK + ql * 128 + cb);
      bf16x8 k1 = *(const bf16x8*)(sK + (ql + 32) * 128 + cb);
      st0 = __builtin_amdgcn_mfma_f32_32x32x16_bf16(k0, qf[ks], st0, 0, 0, 0);
      st1 = __builtin_amdgcn_mfma_f32_32x32x16_bf16(k1, qf[ks], st1, 0, 0, 0);
    }
    __builtin_amdgcn_s_setprio(0);

    // ---- online softmax with defer-max (T13)
    float mx = fmaxf(st0[0], st1[0]);
    #pragma unroll
    for (int r = 1; r < 16; ++r) mx = fmaxf(mx, fmaxf(st0[r], st1[r]));
    mx = fmaxf(mx, __shfl_xor(mx, 32));
    if (!__all(mx <= m_run + 8.0f)) {
      float mn = fmaxf(m_run, mx);
      float al = exp2f(m_run - mn);
      m_run = mn;
      l_run *= al;
      #pragma unroll
      for (int r = 0; r < 16; ++r) { ot0[r] *= al; ot1[r] *= al; }
    }
    float p0[16], p1[16];
    float rs = 0.0f;
    #pragma unroll
    for (int r = 0; r < 16; ++r) {
      p0[r] = exp2f(st0[r] - m_run);
      p1[r] = exp2f(st1[r] - m_run);
      rs += p0[r] + p1[r];
    }
    rs += __shfl_xor(rs, 32);
    l_run += rs;

    // ---- pack own pairs, exchange packed ints (16 shfl), select
    int pa[8], pb[8], pc[8], pd[8];
    #pragma unroll
    for (int r = 0; r < 8; ++r) pa[r] = pk2(p0[2 * r], p0[2 * r + 1]);
    #pragma unroll
    for (int r = 0; r < 8; ++r) pb[r] = __shfl_xor(pa[r], 32);
    #pragma unroll
    for (int r = 0; r < 8; ++r) pc[r] = pk2(p1[2 * r], p1[2 * r + 1]);
    #pragma unroll
    for (int r = 0; r < 8; ++r) pd[r] = __shfl_xor(pc[r], 32);
    i32x4 paw[4];
    paw[0][0] = hi ? pb[2] : pa[0];  paw[0][1] = hi ? pb[3] : pa[1];
    paw[0][2] = hi ? pa[2] : pb[0];  paw[0][3] = hi ? pa[3] : pb[1];
    paw[1][0] = hi ? pb[6] : pa[4];  paw[1][1] = hi ? pb[7] : pa[5];
    paw[1][2] = hi ? pa[6] : pb[4];  paw[1][3] = hi ? pa[7] : pb[5];
    paw[2][0] = hi ? pd[2] : pc[0];  paw[2][1] = hi ? pd[3] : pc[1];
    paw[2][2] = hi ? pc[2] : pd[0];  paw[2][3] = hi ? pc[3] : pd[1];
    paw[3][0] = hi ? pd[6] : pc[4];  paw[3][1] = hi ? pd[7] : pc[5];
    paw[3][2] = hi ? pc[6] : pd[4];  paw[3][3] = hi ? pc[7] : pd[5];

    // ---- PV: ot = mfma(V, P) -> C[f][q]
    __builtin_amdgcn_s_setprio(1);
    #pragma unroll
    for (int ks = 0; ks < 4; ++ks) {
      int cb = (ks * 32 + hi * 16) ^ SW(ql);
      bf16x8 pf = __builtin_bit_cast(bf16x8, paw[ks]);
      bf16x8 v0 = *(const bf16x8*)(sVt + ql * 128 + cb);
      bf16x8 v1 = *(const bf16x8*)(sVt + (ql + 32) * 128 + cb);
      ot0 = __builtin_amdgcn_mfma_f32_32x32x16_bf16(v0, pf, ot0, 0, 0, 0);
      ot1 = __builtin_amdgcn_mfma_f32_32x32x16_bf16(v1, pf, ot1, 0, 0, 0);
    }
    __builtin_amdgcn_s_setprio(0);

    // ---- write next tile's V^T into the other buffer
    if (kt < 31) {
      char* dvt = smem + nxt * 16384 + 8192;
      #pragma unroll
      for (int f = 0; f < 4; ++f) {
        int fr = vfg * 4 + f;
        u32x2 dw;
        dw[0] = (unsigned short)nv0[f] |
                ((unsigned int)(unsigned short)nv1[f] << 16);
        dw[1] = (unsigned short)nv2[f] |
                ((unsigned int)(unsigned short)nv3[f] << 16);
        *(u32x2*)(dvt + fr * 128 + ((vkg * 8) ^ SW(fr))) = dw;
      }
    }
    __syncthreads();
    cur = nxt;
  }

  // ---- epilogue: normalize, pack bf16 pairs, store
  float inv = 1.0f / l_run;
  short* crow = ctx + ((size_t)b * S_ + qrow) * E_ + h * 64;
  #pragma unroll
  for (int i = 0; i < 8; ++i) {
    int f0 = ((2 * i) & 3) + 8 * (i >> 1) + 4 * hi;  // even, pair (f0, f0+1)
    int w0 = pk2(ot0[2 * i] * inv, ot0[2 * i + 1] * inv);
    int w1 = pk2(ot1[2 * i] * inv, ot1[2 * i + 1] * inv);
    *(int*)(crow + f0)      = w0;
    *(int*)(crow + f0 + 32) = w1;
  }
}

// ---------------- launch -----------------------------------------------------
extern "C" void kernel_launch(void* const* d_in, const int* in_sizes, int n_in,
                              void* d_out, int out_size, void* d_ws, size_t ws_size,
                              hipStream_t stream) {
  const float* x    = (const float*)d_in[0];
  const float* Wqkv = (const float*)d_in[1];
  const float* bqkv = (const float*)d_in[2];
  const float* Wout = (const float*)d_in[3];
  const float* bout = (const float*)d_in[4];

  char* ws = (char*)d_ws;
  short* xb    = (short*)(ws);                          // 8 MB
  short* wqkvb = (short*)(ws + 8388608);                // 6 MB
  short* woutb = (short*)(ws + 8388608 + 6291456);      // 2 MB
  short* qkvb  = (short*)(ws + 16777216);               // 24 MB
  short* ctx   = (short*)(ws + 16777216 + 25165824);    // 8 MB  (total 48 MB)

  cvt_f32_bf16<<<2048, 256, 0, stream>>>(x, xb, (T_ * E_) / 8);
  cvt_f32_bf16<<<1536, 256, 0, stream>>>(Wqkv, wqkvb, (F_ * E_) / 8);
  cvt_f32_bf16<<<512, 256, 0, stream>>>(Wout, woutb, (E_ * E_) / 8);

  gemm_nt<short><<<dim3(F_ / 128, T_ / 128), 256, 0, stream>>>(
      xb, wqkvb, bqkv, qkvb, T_, F_, E_);

  attn_kernel<<<dim3(S_ / 128, H_, B_), 256, 0, stream>>>(qkvb, ctx);

  gemm_nt<float><<<dim3(E_ / 128, T_ / 128), 256, 0, stream>>>(
      ctx, woutb, bout, (float*)d_out, T_, E_, E_);
}